// Round 22
// baseline (80.974 us; speedup 1.0000x reference)
//
#include <hip/hip_runtime.h>
#include <hip/hip_bf16.h>
#include <hip/hip_fp8.h>

// CSSM TinyViT block, fused MFMA implementation for gfx950.
// B=16,H=32,W=32 -> 16384 rows of C=384. T=8, HID=1536.
// Round 22 = round 21 (best, 69.2us) re-tiled to TWO independent blocks/CU:
// 512 blocks of 32 pixels, 512 thr (8 waves, 48 chans/wave), ~69KB LDS each.
// Barrier drains now stall only half the CU's waves; the other block keeps
// the MFMA/VALU pipes fed (r13 retest: barrier-drain fraction is now much
// larger than on the bf16 base). Cost: 2x L2 weight traffic (+~4.7us,
// no HBM change). All r15-r21 fp8/MX machinery unchanged.

#define CCH   384          // global row stride (elements)
#define SBB   432          // LDS row stride in BYTES (16B-aligned)
#define SH    392          // h8 LDS row stride in USHORTS
#define NPIX  16384
#define BMROWS 32          // pixels per block
#define NTHR  512          // 8 waves; wave owns 48 chans x 32 pixels
#define LNEPS 1e-6f
#define HBUF  (BMROWS * SBB)  // 13824 bytes per buffer
#define WSC   64.0f        // weight pre-scale (pack time)
#define ASC   8.0f         // activation scale (LDS store convention)
#define IASC  0.125f       // 1/ASC
#define GSC   0.015625f    // 1/WSC
#define DQ    0.001953125f // 1/(WSC*ASC)
#define SCL1  0x7F7F7F7Fu  // E8M0 scale = 127 in every byte -> 2^0 = 1.0

typedef __attribute__((ext_vector_type(4))) float f4_t;    // 4 x f32
typedef __attribute__((ext_vector_type(8))) int   i32x8;   // 32 B MFMA operand

// workspace offsets (BYTE units). Each 16(chan) x 128(k) fp8 tile = 2048 B.
// K-MAJOR tile order: tile = kb * (N/16) + n16   (kb = K/128 block)
#define OFF_WU 0u
#define OFF_WG 147456u      // 72 tiles * 2048 B
#define OFF_A  294912u
#define OFF_W1 442368u      // 384x1536 -> 288 tiles
#define OFF_W2 1032192u     // 1536x384 -> 288 tiles

__device__ __forceinline__ unsigned char f2e4(float f) {
  __hip_fp8_e4m3 t(f);                       // OCP e4m3fn, HW cvt on gfx950
  return (unsigned char)t.__x;
}

#if __has_builtin(__builtin_amdgcn_cvt_pk_fp8_f32)
__device__ __forceinline__ unsigned pk4e4(float a, float b, float c, float d) {
  int v = __builtin_amdgcn_cvt_pk_fp8_f32(a, b, 0, false);
  v = __builtin_amdgcn_cvt_pk_fp8_f32(c, d, v, true);
  return (unsigned)v;
}
#else
__device__ __forceinline__ unsigned pk4e4(float a, float b, float c, float d) {
  return (unsigned)f2e4(a) | ((unsigned)f2e4(b) << 8)
       | ((unsigned)f2e4(c) << 16) | ((unsigned)f2e4(d) << 24);
}
#endif

// raw HW exp2 (v_exp_f32); inputs bounded in this kernel -> no guards needed
#if __has_builtin(__builtin_amdgcn_exp2f)
__device__ __forceinline__ float fexp2(float x) { return __builtin_amdgcn_exp2f(x); }
#else
__device__ __forceinline__ float fexp2(float x) { return exp2f(x); }
#endif

__device__ __forceinline__ unsigned short f2bf(float f) {
  return __builtin_bit_cast(unsigned short, __float2bfloat16(f));
}
__device__ __forceinline__ unsigned pack2(float lo, float hi) {
  return (unsigned)f2bf(lo) | ((unsigned)f2bf(hi) << 16);
}
__device__ __forceinline__ float ulo(unsigned u) {
  union { unsigned x; float f; } v; v.x = u << 16; return v.f;
}
__device__ __forceinline__ float uhi(unsigned u) {
  union { unsigned x; float f; } v; v.x = u & 0xffff0000u; return v.f;
}
// sigmoid(z) = 1/(1+2^(-z*log2e))
__device__ __forceinline__ float fsigmoid(float z) {
  return __builtin_amdgcn_rcpf(1.f + fexp2(z * -1.44269504088896f));
}

// Pack all five f32 weights into fp8 MFMA-A fragment order, K=128 tiles:
// P[off + tile*2048 + lane*32 + j] =
//   e4m3(WSC * W[kb*128 + (lane>>4)*32 + j][n16*16 + (lane&15)]), j=0..31
__global__ void pack_all(const float* __restrict__ Wu, const float* __restrict__ Wg,
                         const float* __restrict__ A,  const float* __restrict__ W1,
                         const float* __restrict__ W2, unsigned char* __restrict__ P) {
  const int gid = blockIdx.x * blockDim.x + threadIdx.x;
  const int l = gid & 63;
  int tile = gid >> 6;
  const float* W; int N; unsigned off; int t;
  if      (tile <  72) { W = Wu; N = 384;  off = OFF_WU; t = tile;       }
  else if (tile < 144) { W = Wg; N = 384;  off = OFF_WG; t = tile - 72;  }
  else if (tile < 216) { W = A;  N = 384;  off = OFF_A;  t = tile - 144; }
  else if (tile < 504) { W = W1; N = 1536; off = OFF_W1; t = tile - 216; }
  else if (tile < 792) { W = W2; N = 384;  off = OFF_W2; t = tile - 504; }
  else return;
  const int ntn = N >> 4;
  const int kb  = t / ntn, n16 = t % ntn;
  const int krow = kb * 128 + ((l >> 4) << 5);
  const int col  = n16 * 16 + (l & 15);
  unsigned pk[8];
  #pragma unroll
  for (int d = 0; d < 8; ++d) {
    unsigned v = 0;
    #pragma unroll
    for (int j = 0; j < 4; ++j)
      v |= (unsigned)f2e4(W[(size_t)(krow + d * 4 + j) * N + col] * WSC) << (8 * j);
    pk[d] = v;
  }
  unsigned* dst = reinterpret_cast<unsigned*>(P + off + ((size_t)t << 11) + (l << 5));
  #pragma unroll
  for (int d = 0; d < 8; ++d) dst[d] = pk[d];
}

// acc[2][3] += W^T(3 chan-tiles, packed fp8 K=128) * X^T(LDS fp8, 2 pixel-tiles)
// via MX-scaled MFMA with unit scales. NKB counts K/128 blocks (=3 for K=384).
template <int NKB>
__device__ __forceinline__ void gemm_acc(const unsigned char* sb,
                                         const unsigned char* __restrict__ wt,
                                         int kb0, int ntn, int n16base,
                                         int lane, f4_t acc[2][3]) {
  const int r    = lane & 15;
  const int koff = (lane >> 4) << 5;        // byte offset of 32-k group
  __builtin_amdgcn_s_setprio(1);
  #pragma unroll 1
  for (int kb = 0; kb < NKB; ++kb) {
    const int ac = kb * 128 + koff;
    i32x8 p[2];
    p[0] = *reinterpret_cast<const i32x8*>(&sb[r * SBB + ac]);
    p[1] = *reinterpret_cast<const i32x8*>(&sb[(16 + r) * SBB + ac]);
    const unsigned char* bt =
        wt + (((size_t)((kb0 + kb) * ntn + n16base)) << 11) + (lane << 5);
    #pragma unroll
    for (int ct = 0; ct < 3; ++ct) {
      const i32x8 w = *reinterpret_cast<const i32x8*>(bt + ((size_t)ct << 11));
      acc[0][ct] = __builtin_amdgcn_mfma_scale_f32_16x16x128_f8f6f4(
          w, p[0], acc[0][ct], 0, 0, 0, (int)SCL1, 0, (int)SCL1);
      acc[1][ct] = __builtin_amdgcn_mfma_scale_f32_16x16x128_f8f6f4(
          w, p[1], acc[1][ct], 0, 0, 0, (int)SCL1, 0, (int)SCL1);
    }
  }
  __builtin_amdgcn_s_setprio(0);
}

// write pre-scaled C/D tile into fp8 LDS [pix][chan]: 2 cvt_pk + 1 write/quad.
__device__ __forceinline__ void write_tile(unsigned char* sb, const f4_t t[2][3],
                                           int ch0, int lane) {
  const int pixb = lane & 15;
  #pragma unroll
  for (int pt = 0; pt < 2; ++pt) {
    const int pix = pt * 16 + pixb;
    #pragma unroll
    for (int ct = 0; ct < 3; ++ct) {
      const unsigned v = pk4e4(t[pt][ct][0], t[pt][ct][1],
                               t[pt][ct][2], t[pt][ct][3]);
      *reinterpret_cast<unsigned*>(&sb[pix * SBB + ch0 + ct * 16]) = v;
    }
  }
}

__device__ __forceinline__ void zero_acc(f4_t a[2][3]) {
  #pragma unroll
  for (int pt = 0; pt < 2; ++pt)
    #pragma unroll
    for (int ct = 0; ct < 3; ++ct) a[pt][ct] = (f4_t){0.f, 0.f, 0.f, 0.f};
}

__global__ __launch_bounds__(NTHR)
__attribute__((amdgpu_waves_per_eu(4)))
void cssm_main(
    const float* __restrict__ x,
    const float* __restrict__ n1s, const float* __restrict__ n1b,
    const float* __restrict__ bu, const float* __restrict__ bg,
    const float* __restrict__ n2s, const float* __restrict__ n2b,
    const float* __restrict__ b1, const float* __restrict__ b2,
    const unsigned char* __restrict__ wp,
    float* __restrict__ out) {
  __shared__ unsigned char sm[3 * HBUF];    // bA | bB | bC (13.5KB each)
  __shared__ unsigned short hd[BMROWS * SH];// h8 (bf16, same-thread reread)
  __shared__ float part[BMROWS][8][2];      // per-(pixel,chan-slot) LN2 partials
  __shared__ float srow[BMROWS][2];         // LN2 mu, rs per pixel
  unsigned char* bA = sm;                   // xn -> h ping -> xn2
  unsigned char* bB = sm + HBUF;            // h pong -> m even chunks
  unsigned char* bC = sm + 2 * HBUF;        // m odd chunks

  const int tid = threadIdx.x;
  const int lane = tid & 63;
  const int nw = tid >> 6;                  // chan-slot 0..7: chans nw*48..+47
  const int r0 = blockIdx.x * BMROWS;
  const int pixb = lane & 15;
  const int ch0  = nw * 48 + ((lane >> 4) << 2);   // byte == chan index

  // ---------------- Phase A: LN1(x) -> bA (fp8, ASC-scaled) ----------------
  {
    const int row = tid >> 4, seg = tid & 15;    // 16 thr/row, 24 elems each
    const float* xr = x + (size_t)(r0 + row) * CCH + seg * 24;
    float v[24];
    float s = 0.f, s2 = 0.f;
    #pragma unroll
    for (int i = 0; i < 6; ++i) {
      const f4_t t = reinterpret_cast<const f4_t*>(xr)[i];
      #pragma unroll
      for (int j = 0; j < 4; ++j) { const float f = t[j]; v[i * 4 + j] = f; s += f; s2 += f * f; }
    }
    #pragma unroll
    for (int o = 1; o < 16; o <<= 1) { s += __shfl_xor(s, o, 64); s2 += __shfl_xor(s2, o, 64); }
    const float mu = s * (1.f / CCH);
    const float rs = rsqrtf(fmaxf(s2 * (1.f / CCH) - mu * mu, 0.f) + LNEPS);
    #pragma unroll
    for (int g8 = 0; g8 < 3; ++g8) {
      float w[8];
      #pragma unroll
      for (int j = 0; j < 8; ++j) {
        const int colc = seg * 24 + g8 * 8 + j;
        w[j] = ((v[g8 * 8 + j] - mu) * rs * n1s[colc] + n1b[colc]) * ASC;
      }
      uint2 pk;
      pk.x = pk4e4(w[0], w[1], w[2], w[3]);
      pk.y = pk4e4(w[4], w[5], w[6], w[7]);
      *reinterpret_cast<uint2*>(&bA[row * SBB + seg * 24 + g8 * 8]) = pk;
    }
  }
  __syncthreads();

  // ---------------- Phase A2: gf = g/WSC, cf = ASC*c (f32 regs); h1 -> bB --
  f4_t acc[2][3], gf[2][3], cf[2][3];
  zero_acc(acc);
  gemm_acc<3>(bA, wp + OFF_WG, 0, 24, nw * 3, lane, acc);
  #pragma unroll
  for (int ct = 0; ct < 3; ++ct) {
    const f4_t bgq = *reinterpret_cast<const f4_t*>(&bg[ch0 + ct * 16]);
    #pragma unroll
    for (int pt = 0; pt < 2; ++pt)
      #pragma unroll
      for (int j = 0; j < 4; ++j)
        gf[pt][ct][j] = fsigmoid(acc[pt][ct][j] * DQ + bgq[j]);   // g itself
  }
  zero_acc(acc);
  gemm_acc<3>(bA, wp + OFF_WU, 0, 24, nw * 3, lane, acc);
  #pragma unroll
  for (int ct = 0; ct < 3; ++ct) {
    const f4_t buq = *reinterpret_cast<const f4_t*>(&bu[ch0 + ct * 16]);
    #pragma unroll
    for (int pt = 0; pt < 2; ++pt)
      #pragma unroll
      for (int j = 0; j < 4; ++j) {
        const float g = gf[pt][ct][j];
        cf[pt][ct][j] = (1.f - g) * (acc[pt][ct][j] * DQ + buq[j]) * ASC;
        gf[pt][ct][j] = g * GSC;
      }
  }
  write_tile(bB, cf, ch0, lane);            // H1 = ASC*c  (bA reads done)
  __syncthreads();

  // ---------------- Phase B: H' = gf*raw + cf, ping-pong bB/bA -------------
  {
    unsigned char* cur = bB;
    unsigned char* alt = bA;
    #pragma unroll 1
    for (int stp = 0; stp < 7; ++stp) {     // h2..h8
      zero_acc(acc);
      gemm_acc<3>(cur, wp + OFF_A, 0, 24, nw * 3, lane, acc);
      #pragma unroll
      for (int pt = 0; pt < 2; ++pt)
        #pragma unroll
        for (int ct = 0; ct < 3; ++ct)
          #pragma unroll
          for (int j = 0; j < 4; ++j)
            acc[pt][ct][j] = gf[pt][ct][j] * acc[pt][ct][j] + cf[pt][ct][j];
      if (stp < 6) {
        write_tile(alt, acc, ch0, lane);    // write buffer nobody is reading
        unsigned char* t = cur; cur = alt; alt = t;
        __syncthreads();
      }
    }
  }
  // last recurrence reads hit bB (fenced later); bA reads fenced at stp5.

  // ------- Phase C: h8 -> hd (bf16); y = x + h8 (regs); LN2 -> xn2 in bA ---
  #pragma unroll
  for (int pt = 0; pt < 2; ++pt) {
    const int pix = pt * 16 + pixb;
    float s = 0.f, s2 = 0.f;
    #pragma unroll
    for (int ct = 0; ct < 3; ++ct) {
      const size_t pos = (size_t)(r0 + pix) * CCH + ch0 + ct * 16;
      const f4_t xq = *reinterpret_cast<const f4_t*>(&x[pos]);
      uint2 hq;
      float h0 = acc[pt][ct][0] * IASC, h1 = acc[pt][ct][1] * IASC;
      float h2 = acc[pt][ct][2] * IASC, h3 = acc[pt][ct][3] * IASC;
      hq.x = pack2(h0, h1); hq.y = pack2(h2, h3);
      *reinterpret_cast<uint2*>(&hd[pix * SH + ch0 + ct * 16]) = hq;
      const float y0 = xq[0] + h0, y1 = xq[1] + h1;
      const float y2 = xq[2] + h2, y3 = xq[3] + h3;
      acc[pt][ct][0] = y0; acc[pt][ct][1] = y1;
      acc[pt][ct][2] = y2; acc[pt][ct][3] = y3;
      s += y0 + y1 + y2 + y3;
      s2 += y0 * y0 + y1 * y1 + y2 * y2 + y3 * y3;
    }
    s += __shfl_xor(s, 16, 64); s2 += __shfl_xor(s2, 16, 64);
    s += __shfl_xor(s, 32, 64); s2 += __shfl_xor(s2, 32, 64);
    if (lane < 16) { part[pix][nw][0] = s; part[pix][nw][1] = s2; }
  }
  __syncthreads();
  if (tid < BMROWS) {
    float s = 0.f, s2 = 0.f;
    #pragma unroll
    for (int w = 0; w < 8; ++w) { s += part[tid][w][0]; s2 += part[tid][w][1]; }
    const float mu = s * (1.f / CCH);
    srow[tid][0] = mu;
    srow[tid][1] = rsqrtf(fmaxf(s2 * (1.f / CCH) - mu * mu, 0.f) + LNEPS);
  }
  __syncthreads();
  {
    f4_t scq[3], bsq[3];
    #pragma unroll
    for (int ct = 0; ct < 3; ++ct) {
      const f4_t sc = *reinterpret_cast<const f4_t*>(&n2s[ch0 + ct * 16]);
      const f4_t bs = *reinterpret_cast<const f4_t*>(&n2b[ch0 + ct * 16]);
      #pragma unroll
      for (int j = 0; j < 4; ++j) { scq[ct][j] = sc[j] * ASC; bsq[ct][j] = bs[j] * ASC; }
    }
    #pragma unroll
    for (int pt = 0; pt < 2; ++pt) {
      const int pix = pt * 16 + pixb;
      const float mu = srow[pix][0], rs = srow[pix][1];
      #pragma unroll
      for (int ct = 0; ct < 3; ++ct)
        #pragma unroll
        for (int j = 0; j < 4; ++j)
          acc[pt][ct][j] = (acc[pt][ct][j] - mu) * rs * scq[ct][j] + bsq[ct][j];
    }
    write_tile(bA, acc, ch0, lane);         // ASC*xn2 (bA reads fenced at stp5)
  }
  __syncthreads();

  // ------- Phase D: MLP in 4 HID-chunks, m double-buffered bB/bC -----------
  f4_t aco[2][3];
  zero_acc(aco);                            // MFMA-only until E -> AGPR
  #pragma unroll 1
  for (int ch = 0; ch < 4; ++ch) {
    unsigned char* buf = (ch & 1) ? bC : bB;
    zero_acc(acc);
    gemm_acc<3>(bA, wp + OFF_W1, 0, 96, ch * 24 + nw * 3, lane, acc);
    #pragma unroll
    for (int ct = 0; ct < 3; ++ct) {
      const f4_t b1q = *reinterpret_cast<const f4_t*>(&b1[ch * 384 + ch0 + ct * 16]);
      #pragma unroll
      for (int pt = 0; pt < 2; ++pt)
        #pragma unroll
        for (int j = 0; j < 4; ++j) {
          // gelu(z) = z / (1 + 2^(-2.3021178*(z + 0.044715 z^3))); store ASC*gelu
          const float z = acc[pt][ct][j] * DQ + b1q[j];
          const float m = z * z;
          const float t = z * fmaf(m, 0.044715f, 1.0f);
          const float e = fexp2(t * -2.30211774f);
          acc[pt][ct][j] = (z * ASC) * __builtin_amdgcn_rcpf(1.f + e);
        }
    }
    write_tile(buf, acc, ch0, lane);
    __syncthreads();                        // buf complete; prev buf readers
                                            // passed the previous barrier
    gemm_acc<3>(buf, wp + OFF_W2, ch * 3, 24, nw * 3, lane, aco);
  }

  // ------- Phase E: out = x + h8 + DQ*mlp + b2 (x L3-warm, h8 from LDS) ----
  {
    f4_t b2q[3];
    #pragma unroll
    for (int ct = 0; ct < 3; ++ct)
      b2q[ct] = *reinterpret_cast<const f4_t*>(&b2[ch0 + ct * 16]);
    #pragma unroll
    for (int pt = 0; pt < 2; ++pt) {
      const int pix = pt * 16 + pixb;
      #pragma unroll
      for (int ct = 0; ct < 3; ++ct) {
        const size_t pos = (size_t)(r0 + pix) * CCH + ch0 + ct * 16;
        const f4_t xq = *reinterpret_cast<const f4_t*>(&x[pos]);
        const uint2 hq = *reinterpret_cast<const uint2*>(&hd[pix * SH + ch0 + ct * 16]);
        f4_t o;
        o[0] = xq[0] + ulo(hq.x) + aco[pt][ct][0] * DQ + b2q[ct][0];
        o[1] = xq[1] + uhi(hq.x) + aco[pt][ct][1] * DQ + b2q[ct][1];
        o[2] = xq[2] + ulo(hq.y) + aco[pt][ct][2] * DQ + b2q[ct][2];
        o[3] = xq[3] + uhi(hq.y) + aco[pt][ct][3] * DQ + b2q[ct][3];
        *reinterpret_cast<f4_t*>(&out[pos]) = o;
      }
    }
  }
}

extern "C" void kernel_launch(void* const* d_in, const int* in_sizes, int n_in,
                              void* d_out, int out_size, void* d_ws, size_t ws_size,
                              hipStream_t stream) {
  const float* x   = (const float*)d_in[0];
  const float* n1s = (const float*)d_in[1];
  const float* n1b = (const float*)d_in[2];
  const float* Wu  = (const float*)d_in[3];
  const float* bu  = (const float*)d_in[4];
  const float* Wg  = (const float*)d_in[5];
  const float* bg  = (const float*)d_in[6];
  const float* A   = (const float*)d_in[7];
  const float* n2s = (const float*)d_in[8];
  const float* n2b = (const float*)d_in[9];
  const float* W1  = (const float*)d_in[10];
  const float* b1  = (const float*)d_in[11];
  const float* W2  = (const float*)d_in[12];
  const float* b2  = (const float*)d_in[13];
  unsigned char* wp = (unsigned char*)d_ws;
  float* out = (float*)d_out;

  // pack all weights to fp8 K=128 fragment order (792 tiles * 64 lanes)
  pack_all<<<(792 * 64) / 256, 256, 0, stream>>>(Wu, Wg, A, W1, W2, wp);

  cssm_main<<<NPIX / BMROWS, NTHR, 0, stream>>>(
      x, n1s, n1b, bu, bg, n2s, n2b, b1, b2, wp, out);
}

// Round 23
// 68.535 us; speedup vs baseline: 1.1815x; 1.1815x over previous
//
#include <hip/hip_runtime.h>
#include <hip/hip_bf16.h>
#include <hip/hip_fp8.h>

// CSSM TinyViT block, fused MFMA implementation for gfx950.
// B=16,H=32,W=32 -> 16384 rows of C=384. T=8, HID=1536.
// Round 23 = round 21 (best, 69.2us; r22's 2-block split regressed again) +
// dequant constants folded into the MX E8M0 scale operands (were unit):
// Wg/W1/W2 use 2^-9 (true-unit outputs, no *DQ), Wu/A use 2^-6 (outputs
// pre-scaled xASC, no *ASC / GSC folds). Bit-exact; ~250 VALU ops/thread off.

#define CCH   384          // global row stride (elements)
#define SBB   432          // LDS row stride in BYTES (16B-aligned)
#define SH    392          // h8 LDS row stride in USHORTS
#define NPIX  16384
#define BMROWS 64          // pixels per block
#define NTHR  768          // 12 waves; wave owns 32 chans x 64 pixels
#define LNEPS 1e-6f
#define HBUF  (BMROWS * SBB)  // 27648 bytes per buffer
#define WSC   64.0f        // weight pre-scale (pack time)
#define ASC   8.0f         // activation scale (LDS store convention)
#define IASC  0.125f       // 1/ASC
#define SCL1  0x7F7F7F7Fu  // E8M0 127 -> 2^0  = 1
#define SCLDQ 0x76767676u  // E8M0 118 -> 2^-9 = DQ   (true-unit output)
#define SCLA6 0x79797979u  // E8M0 121 -> 2^-6        (ASC-unit output)

typedef __attribute__((ext_vector_type(4))) float f4_t;    // 4 x f32
typedef __attribute__((ext_vector_type(8))) int   i32x8;   // 32 B MFMA operand

// workspace offsets (BYTE units). Each 16(chan) x 128(k) fp8 tile = 2048 B.
// K-MAJOR tile order: tile = kb * (N/16) + n16   (kb = K/128 block)
#define OFF_WU 0u
#define OFF_WG 147456u      // 72 tiles * 2048 B
#define OFF_A  294912u
#define OFF_W1 442368u      // 384x1536 -> 288 tiles
#define OFF_W2 1032192u     // 1536x384 -> 288 tiles

__device__ __forceinline__ unsigned char f2e4(float f) {
  __hip_fp8_e4m3 t(f);                       // OCP e4m3fn, HW cvt on gfx950
  return (unsigned char)t.__x;
}

#if __has_builtin(__builtin_amdgcn_cvt_pk_fp8_f32)
__device__ __forceinline__ unsigned pk4e4(float a, float b, float c, float d) {
  int v = __builtin_amdgcn_cvt_pk_fp8_f32(a, b, 0, false);
  v = __builtin_amdgcn_cvt_pk_fp8_f32(c, d, v, true);
  return (unsigned)v;
}
#else
__device__ __forceinline__ unsigned pk4e4(float a, float b, float c, float d) {
  return (unsigned)f2e4(a) | ((unsigned)f2e4(b) << 8)
       | ((unsigned)f2e4(c) << 16) | ((unsigned)f2e4(d) << 24);
}
#endif

// raw HW exp2 (v_exp_f32); inputs bounded in this kernel -> no guards needed
#if __has_builtin(__builtin_amdgcn_exp2f)
__device__ __forceinline__ float fexp2(float x) { return __builtin_amdgcn_exp2f(x); }
#else
__device__ __forceinline__ float fexp2(float x) { return exp2f(x); }
#endif

__device__ __forceinline__ unsigned short f2bf(float f) {
  return __builtin_bit_cast(unsigned short, __float2bfloat16(f));
}
__device__ __forceinline__ unsigned pack2(float lo, float hi) {
  return (unsigned)f2bf(lo) | ((unsigned)f2bf(hi) << 16);
}
__device__ __forceinline__ float ulo(unsigned u) {
  union { unsigned x; float f; } v; v.x = u << 16; return v.f;
}
__device__ __forceinline__ float uhi(unsigned u) {
  union { unsigned x; float f; } v; v.x = u & 0xffff0000u; return v.f;
}
// sigmoid(z) = 1/(1+2^(-z*log2e))
__device__ __forceinline__ float fsigmoid(float z) {
  return __builtin_amdgcn_rcpf(1.f + fexp2(z * -1.44269504088896f));
}

// Pack all five f32 weights into fp8 MFMA-A fragment order, K=128 tiles:
// P[off + tile*2048 + lane*32 + j] =
//   e4m3(WSC * W[kb*128 + (lane>>4)*32 + j][n16*16 + (lane&15)]), j=0..31
__global__ void pack_all(const float* __restrict__ Wu, const float* __restrict__ Wg,
                         const float* __restrict__ A,  const float* __restrict__ W1,
                         const float* __restrict__ W2, unsigned char* __restrict__ P) {
  const int gid = blockIdx.x * blockDim.x + threadIdx.x;
  const int l = gid & 63;
  int tile = gid >> 6;
  const float* W; int N; unsigned off; int t;
  if      (tile <  72) { W = Wu; N = 384;  off = OFF_WU; t = tile;       }
  else if (tile < 144) { W = Wg; N = 384;  off = OFF_WG; t = tile - 72;  }
  else if (tile < 216) { W = A;  N = 384;  off = OFF_A;  t = tile - 144; }
  else if (tile < 504) { W = W1; N = 1536; off = OFF_W1; t = tile - 216; }
  else if (tile < 792) { W = W2; N = 384;  off = OFF_W2; t = tile - 504; }
  else return;
  const int ntn = N >> 4;
  const int kb  = t / ntn, n16 = t % ntn;
  const int krow = kb * 128 + ((l >> 4) << 5);
  const int col  = n16 * 16 + (l & 15);
  unsigned pk[8];
  #pragma unroll
  for (int d = 0; d < 8; ++d) {
    unsigned v = 0;
    #pragma unroll
    for (int j = 0; j < 4; ++j)
      v |= (unsigned)f2e4(W[(size_t)(krow + d * 4 + j) * N + col] * WSC) << (8 * j);
    pk[d] = v;
  }
  unsigned* dst = reinterpret_cast<unsigned*>(P + off + ((size_t)t << 11) + (l << 5));
  #pragma unroll
  for (int d = 0; d < 8; ++d) dst[d] = pk[d];
}

// acc[4][2] += scale * W^T(2 chan-tiles, fp8 K=128) * X^T(LDS fp8, 4 pixel-
// tiles) via MX-scaled MFMA; scl is the E8M0 per-block scale for the weight
// operand (power-of-2 dequant folded into HW). NKB = K/128 blocks.
template <int NKB>
__device__ __forceinline__ void gemm_acc(const unsigned char* sb,
                                         const unsigned char* __restrict__ wt,
                                         int kb0, int ntn, int n16base,
                                         int lane, unsigned scl, f4_t acc[4][2]) {
  const int r    = lane & 15;
  const int koff = (lane >> 4) << 5;        // byte offset of 32-k group
  __builtin_amdgcn_s_setprio(1);
  #pragma unroll 1
  for (int kb = 0; kb < NKB; ++kb) {
    const int ac = kb * 128 + koff;
    i32x8 p[4];
    #pragma unroll
    for (int pt = 0; pt < 4; ++pt)
      p[pt] = *reinterpret_cast<const i32x8*>(&sb[(pt * 16 + r) * SBB + ac]);
    const unsigned char* bt =
        wt + (((size_t)((kb0 + kb) * ntn + n16base)) << 11) + (lane << 5);
    #pragma unroll
    for (int ct = 0; ct < 2; ++ct) {
      const i32x8 w = *reinterpret_cast<const i32x8*>(bt + (ct << 11));
      #pragma unroll
      for (int pt = 0; pt < 4; ++pt)
        acc[pt][ct] = __builtin_amdgcn_mfma_scale_f32_16x16x128_f8f6f4(
            w, p[pt], acc[pt][ct], 0 /*fmtA=fp8*/, 0 /*fmtB=fp8*/,
            0, (int)scl, 0, (int)SCL1);
    }
  }
  __builtin_amdgcn_s_setprio(0);
}

// write pre-scaled C/D tile into fp8 LDS [pix][chan]: 2 cvt_pk + 1 write/quad.
__device__ __forceinline__ void write_tile(unsigned char* sb, const f4_t t[4][2],
                                           int ch0, int lane) {
  const int pixb = lane & 15;
  #pragma unroll
  for (int pt = 0; pt < 4; ++pt) {
    const int pix = pt * 16 + pixb;
    #pragma unroll
    for (int ct = 0; ct < 2; ++ct) {
      const unsigned v = pk4e4(t[pt][ct][0], t[pt][ct][1],
                               t[pt][ct][2], t[pt][ct][3]);
      *reinterpret_cast<unsigned*>(&sb[pix * SBB + ch0 + ct * 16]) = v;
    }
  }
}

__device__ __forceinline__ void zero_acc(f4_t a[4][2]) {
  #pragma unroll
  for (int pt = 0; pt < 4; ++pt)
    #pragma unroll
    for (int ct = 0; ct < 2; ++ct) a[pt][ct] = (f4_t){0.f, 0.f, 0.f, 0.f};
}

__global__ __launch_bounds__(NTHR)
__attribute__((amdgpu_waves_per_eu(3)))
void cssm_main(
    const float* __restrict__ x,
    const float* __restrict__ n1s, const float* __restrict__ n1b,
    const float* __restrict__ bu, const float* __restrict__ bg,
    const float* __restrict__ n2s, const float* __restrict__ n2b,
    const float* __restrict__ b1, const float* __restrict__ b2,
    const unsigned char* __restrict__ wp,
    float* __restrict__ out) {
  __shared__ unsigned char sm[3 * HBUF];    // bA | bB | bC (27KB each)
  __shared__ unsigned short hd[BMROWS * SH];// h8 (bf16, same-thread reread)
  __shared__ float part[BMROWS][12][2];     // per-(pixel,chan-slot) LN2 partials
  __shared__ float srow[BMROWS][2];         // LN2 mu, rs per pixel
  unsigned char* bA = sm;                   // xn -> h ping -> xn2
  unsigned char* bB = sm + HBUF;            // h pong -> m even chunks
  unsigned char* bC = sm + 2 * HBUF;        // m odd chunks

  const int tid = threadIdx.x;
  const int lane = tid & 63;
  const int nw = tid >> 6;                  // chan-slot 0..11: chans nw*32..+31
  const int r0 = blockIdx.x * BMROWS;
  const int pixb = lane & 15;
  const int ch0  = nw * 32 + ((lane >> 4) << 2);   // byte == chan index

  // ---------------- Phase A: LN1(x) -> bA (fp8, ASC-scaled) ----------------
  if (tid < 512) {
    const int row = tid >> 3, seg = tid & 7;     // 8 thr/row, 48 elems each
    const float* xr = x + (size_t)(r0 + row) * CCH + seg * 48;
    float v[48];
    float s = 0.f, s2 = 0.f;
    #pragma unroll
    for (int i = 0; i < 12; ++i) {
      const f4_t t = reinterpret_cast<const f4_t*>(xr)[i];
      #pragma unroll
      for (int j = 0; j < 4; ++j) { const float f = t[j]; v[i * 4 + j] = f; s += f; s2 += f * f; }
    }
    #pragma unroll
    for (int o = 1; o < 8; o <<= 1) { s += __shfl_xor(s, o, 64); s2 += __shfl_xor(s2, o, 64); }
    const float mu = s * (1.f / CCH);
    const float rs = rsqrtf(fmaxf(s2 * (1.f / CCH) - mu * mu, 0.f) + LNEPS);
    #pragma unroll
    for (int g8 = 0; g8 < 6; ++g8) {
      float w[8];
      #pragma unroll
      for (int j = 0; j < 8; ++j) {
        const int colc = seg * 48 + g8 * 8 + j;
        w[j] = ((v[g8 * 8 + j] - mu) * rs * n1s[colc] + n1b[colc]) * ASC;
      }
      uint2 pk;
      pk.x = pk4e4(w[0], w[1], w[2], w[3]);
      pk.y = pk4e4(w[4], w[5], w[6], w[7]);
      *reinterpret_cast<uint2*>(&bA[row * SBB + seg * 48 + g8 * 8]) = pk;
    }
  }
  __syncthreads();

  // ------- Phase A2: g (true units), cf = ASC*c (HW-scaled); h1 -> bB ------
  f4_t acc[4][2], gf[4][2], cf[4][2];
  zero_acc(acc);
  gemm_acc<3>(bA, wp + OFF_WG, 0, 24, nw * 2, lane, SCLDQ, acc);   // true units
  #pragma unroll
  for (int ct = 0; ct < 2; ++ct) {
    const f4_t bgq = *reinterpret_cast<const f4_t*>(&bg[ch0 + ct * 16]);
    #pragma unroll
    for (int pt = 0; pt < 4; ++pt)
      #pragma unroll
      for (int j = 0; j < 4; ++j)
        gf[pt][ct][j] = fsigmoid(acc[pt][ct][j] + bgq[j]);         // g itself
  }
  zero_acc(acc);
  gemm_acc<3>(bA, wp + OFF_WU, 0, 24, nw * 2, lane, SCLA6, acc);   // ASC units
  #pragma unroll
  for (int ct = 0; ct < 2; ++ct) {
    const f4_t bq = *reinterpret_cast<const f4_t*>(&bu[ch0 + ct * 16]);
    f4_t buA;
    #pragma unroll
    for (int j = 0; j < 4; ++j) buA[j] = bq[j] * ASC;
    #pragma unroll
    for (int pt = 0; pt < 4; ++pt)
      #pragma unroll
      for (int j = 0; j < 4; ++j)
        cf[pt][ct][j] = (1.f - gf[pt][ct][j]) * (acc[pt][ct][j] + buA[j]);
  }
  write_tile(bB, cf, ch0, lane);            // H1 = ASC*c  (bA reads done)
  __syncthreads();

  // ----- Phase B: H' = g*out + cf (out pre-scaled to ASC units by HW) ------
  {
    unsigned char* cur = bB;
    unsigned char* alt = bA;
    #pragma unroll 1
    for (int stp = 0; stp < 7; ++stp) {     // h2..h8
      zero_acc(acc);
      gemm_acc<3>(cur, wp + OFF_A, 0, 24, nw * 2, lane, SCLA6, acc);
      #pragma unroll
      for (int pt = 0; pt < 4; ++pt)
        #pragma unroll
        for (int ct = 0; ct < 2; ++ct)
          #pragma unroll
          for (int j = 0; j < 4; ++j)
            acc[pt][ct][j] = gf[pt][ct][j] * acc[pt][ct][j] + cf[pt][ct][j];
      if (stp < 6) {
        write_tile(alt, acc, ch0, lane);    // write buffer nobody is reading
        unsigned char* t = cur; cur = alt; alt = t;
        __syncthreads();
      }
    }
  }
  // last recurrence reads hit bB (fenced later); bA reads fenced at stp5.

  // ------- Phase C: h8 -> hd (bf16); y = x + h8 (regs); LN2 -> xn2 in bA ---
  #pragma unroll
  for (int pt = 0; pt < 4; ++pt) {
    const int pix = pt * 16 + pixb;
    float s = 0.f, s2 = 0.f;
    #pragma unroll
    for (int ct = 0; ct < 2; ++ct) {
      const size_t pos = (size_t)(r0 + pix) * CCH + ch0 + ct * 16;
      const f4_t xq = *reinterpret_cast<const f4_t*>(&x[pos]);
      uint2 hq;
      float h0 = acc[pt][ct][0] * IASC, h1 = acc[pt][ct][1] * IASC;
      float h2 = acc[pt][ct][2] * IASC, h3 = acc[pt][ct][3] * IASC;
      hq.x = pack2(h0, h1); hq.y = pack2(h2, h3);
      *reinterpret_cast<uint2*>(&hd[pix * SH + ch0 + ct * 16]) = hq;
      const float y0 = xq[0] + h0, y1 = xq[1] + h1;
      const float y2 = xq[2] + h2, y3 = xq[3] + h3;
      acc[pt][ct][0] = y0; acc[pt][ct][1] = y1;
      acc[pt][ct][2] = y2; acc[pt][ct][3] = y3;
      s += y0 + y1 + y2 + y3;
      s2 += y0 * y0 + y1 * y1 + y2 * y2 + y3 * y3;
    }
    s += __shfl_xor(s, 16, 64); s2 += __shfl_xor(s2, 16, 64);
    s += __shfl_xor(s, 32, 64); s2 += __shfl_xor(s2, 32, 64);
    if (lane < 16) { part[pix][nw][0] = s; part[pix][nw][1] = s2; }
  }
  __syncthreads();
  if (tid < BMROWS) {
    float s = 0.f, s2 = 0.f;
    #pragma unroll
    for (int w = 0; w < 12; ++w) { s += part[tid][w][0]; s2 += part[tid][w][1]; }
    const float mu = s * (1.f / CCH);
    srow[tid][0] = mu;
    srow[tid][1] = rsqrtf(fmaxf(s2 * (1.f / CCH) - mu * mu, 0.f) + LNEPS);
  }
  __syncthreads();
  {
    f4_t scq[2], bsq[2];
    #pragma unroll
    for (int ct = 0; ct < 2; ++ct) {
      const f4_t sc = *reinterpret_cast<const f4_t*>(&n2s[ch0 + ct * 16]);
      const f4_t bs = *reinterpret_cast<const f4_t*>(&n2b[ch0 + ct * 16]);
      #pragma unroll
      for (int j = 0; j < 4; ++j) { scq[ct][j] = sc[j] * ASC; bsq[ct][j] = bs[j] * ASC; }
    }
    #pragma unroll
    for (int pt = 0; pt < 4; ++pt) {
      const int pix = pt * 16 + pixb;
      const float mu = srow[pix][0], rs = srow[pix][1];
      #pragma unroll
      for (int ct = 0; ct < 2; ++ct)
        #pragma unroll
        for (int j = 0; j < 4; ++j)
          acc[pt][ct][j] = (acc[pt][ct][j] - mu) * rs * scq[ct][j] + bsq[ct][j];
    }
    write_tile(bA, acc, ch0, lane);         // ASC*xn2 (bA reads fenced at stp5)
  }
  __syncthreads();

  // ------- Phase D: MLP in 4 HID-chunks, m double-buffered bB/bC -----------
  f4_t aco[4][2];
  zero_acc(aco);                            // MFMA-only until E -> AGPR
  #pragma unroll 1
  for (int ch = 0; ch < 4; ++ch) {
    unsigned char* buf = (ch & 1) ? bC : bB;
    zero_acc(acc);
    gemm_acc<3>(bA, wp + OFF_W1, 0, 96, ch * 24 + nw * 2, lane, SCLDQ, acc);
    #pragma unroll
    for (int ct = 0; ct < 2; ++ct) {
      const f4_t b1q = *reinterpret_cast<const f4_t*>(&b1[ch * 384 + ch0 + ct * 16]);
      #pragma unroll
      for (int pt = 0; pt < 4; ++pt)
        #pragma unroll
        for (int j = 0; j < 4; ++j) {
          // gelu(z) = z / (1 + 2^(-2.3021178*(z + 0.044715 z^3))); store ASC*gelu
          const float z = acc[pt][ct][j] + b1q[j];        // true units (HW DQ)
          const float m = z * z;
          const float t = z * fmaf(m, 0.044715f, 1.0f);
          const float e = fexp2(t * -2.30211774f);
          acc[pt][ct][j] = (z * ASC) * __builtin_amdgcn_rcpf(1.f + e);
        }
    }
    write_tile(buf, acc, ch0, lane);
    __syncthreads();                        // buf complete; prev buf readers
                                            // passed the previous barrier
    gemm_acc<3>(buf, wp + OFF_W2, ch * 3, 24, nw * 2, lane, SCLDQ, aco);
  }

  // ------- Phase E: out = x + h8 + mlp + b2 (aco already true units) -------
  {
    f4_t b2q[2];
    #pragma unroll
    for (int ct = 0; ct < 2; ++ct)
      b2q[ct] = *reinterpret_cast<const f4_t*>(&b2[ch0 + ct * 16]);
    #pragma unroll
    for (int pt = 0; pt < 4; ++pt) {
      const int pix = pt * 16 + pixb;
      #pragma unroll
      for (int ct = 0; ct < 2; ++ct) {
        const size_t pos = (size_t)(r0 + pix) * CCH + ch0 + ct * 16;
        const f4_t xq = *reinterpret_cast<const f4_t*>(&x[pos]);
        const uint2 hq = *reinterpret_cast<const uint2*>(&hd[pix * SH + ch0 + ct * 16]);
        f4_t o;
        o[0] = xq[0] + ulo(hq.x) + aco[pt][ct][0] + b2q[ct][0];
        o[1] = xq[1] + uhi(hq.x) + aco[pt][ct][1] + b2q[ct][1];
        o[2] = xq[2] + ulo(hq.y) + aco[pt][ct][2] + b2q[ct][2];
        o[3] = xq[3] + uhi(hq.y) + aco[pt][ct][3] + b2q[ct][3];
        *reinterpret_cast<f4_t*>(&out[pos]) = o;
      }
    }
  }
}

extern "C" void kernel_launch(void* const* d_in, const int* in_sizes, int n_in,
                              void* d_out, int out_size, void* d_ws, size_t ws_size,
                              hipStream_t stream) {
  const float* x   = (const float*)d_in[0];
  const float* n1s = (const float*)d_in[1];
  const float* n1b = (const float*)d_in[2];
  const float* Wu  = (const float*)d_in[3];
  const float* bu  = (const float*)d_in[4];
  const float* Wg  = (const float*)d_in[5];
  const float* bg  = (const float*)d_in[6];
  const float* A   = (const float*)d_in[7];
  const float* n2s = (const float*)d_in[8];
  const float* n2b = (const float*)d_in[9];
  const float* W1  = (const float*)d_in[10];
  const float* b1  = (const float*)d_in[11];
  const float* W2  = (const float*)d_in[12];
  const float* b2  = (const float*)d_in[13];
  unsigned char* wp = (unsigned char*)d_ws;
  float* out = (float*)d_out;

  // pack all weights to fp8 K=128 fragment order (792 tiles * 64 lanes)
  pack_all<<<(792 * 64) / 256, 256, 0, stream>>>(Wu, Wg, A, W1, W2, wp);

  cssm_main<<<NPIX / BMROWS, NTHR, 0, stream>>>(
      x, n1s, n1b, bu, bg, n2s, n2b, b1, b2, wp, out);
}

// Round 24
// 68.493 us; speedup vs baseline: 1.1822x; 1.0006x over previous
//
#include <hip/hip_runtime.h>
#include <hip/hip_bf16.h>
#include <hip/hip_fp8.h>

// CSSM TinyViT block, fused MFMA implementation for gfx950.
// B=16,H=32,W=32 -> 16384 rows of C=384. T=8, HID=1536.
// Round 24 = round 23 (best, 68.5us) + Wg/Wu gemms merged into one k-pass
// (gemm_acc2): shared xn fragment loads (-24 ds_read_b128/thread), one loop
// + setprio region instead of two. Dual accumulators are AGPR-resident
// MFMA C/D; per-accumulator MFMA order unchanged -> bit-identical output.

#define CCH   384          // global row stride (elements)
#define SBB   432          // LDS row stride in BYTES (16B-aligned)
#define SH    392          // h8 LDS row stride in USHORTS
#define NPIX  16384
#define BMROWS 64          // pixels per block
#define NTHR  768          // 12 waves; wave owns 32 chans x 64 pixels
#define LNEPS 1e-6f
#define HBUF  (BMROWS * SBB)  // 27648 bytes per buffer
#define WSC   64.0f        // weight pre-scale (pack time)
#define ASC   8.0f         // activation scale (LDS store convention)
#define IASC  0.125f       // 1/ASC
#define SCL1  0x7F7F7F7Fu  // E8M0 127 -> 2^0  = 1
#define SCLDQ 0x76767676u  // E8M0 118 -> 2^-9 = DQ   (true-unit output)
#define SCLA6 0x79797979u  // E8M0 121 -> 2^-6        (ASC-unit output)

typedef __attribute__((ext_vector_type(4))) float f4_t;    // 4 x f32
typedef __attribute__((ext_vector_type(8))) int   i32x8;   // 32 B MFMA operand

// workspace offsets (BYTE units). Each 16(chan) x 128(k) fp8 tile = 2048 B.
// K-MAJOR tile order: tile = kb * (N/16) + n16   (kb = K/128 block)
#define OFF_WU 0u
#define OFF_WG 147456u      // 72 tiles * 2048 B
#define OFF_A  294912u
#define OFF_W1 442368u      // 384x1536 -> 288 tiles
#define OFF_W2 1032192u     // 1536x384 -> 288 tiles

__device__ __forceinline__ unsigned char f2e4(float f) {
  __hip_fp8_e4m3 t(f);                       // OCP e4m3fn, HW cvt on gfx950
  return (unsigned char)t.__x;
}

#if __has_builtin(__builtin_amdgcn_cvt_pk_fp8_f32)
__device__ __forceinline__ unsigned pk4e4(float a, float b, float c, float d) {
  int v = __builtin_amdgcn_cvt_pk_fp8_f32(a, b, 0, false);
  v = __builtin_amdgcn_cvt_pk_fp8_f32(c, d, v, true);
  return (unsigned)v;
}
#else
__device__ __forceinline__ unsigned pk4e4(float a, float b, float c, float d) {
  return (unsigned)f2e4(a) | ((unsigned)f2e4(b) << 8)
       | ((unsigned)f2e4(c) << 16) | ((unsigned)f2e4(d) << 24);
}
#endif

// raw HW exp2 (v_exp_f32); inputs bounded in this kernel -> no guards needed
#if __has_builtin(__builtin_amdgcn_exp2f)
__device__ __forceinline__ float fexp2(float x) { return __builtin_amdgcn_exp2f(x); }
#else
__device__ __forceinline__ float fexp2(float x) { return exp2f(x); }
#endif

__device__ __forceinline__ unsigned short f2bf(float f) {
  return __builtin_bit_cast(unsigned short, __float2bfloat16(f));
}
__device__ __forceinline__ unsigned pack2(float lo, float hi) {
  return (unsigned)f2bf(lo) | ((unsigned)f2bf(hi) << 16);
}
__device__ __forceinline__ float ulo(unsigned u) {
  union { unsigned x; float f; } v; v.x = u << 16; return v.f;
}
__device__ __forceinline__ float uhi(unsigned u) {
  union { unsigned x; float f; } v; v.x = u & 0xffff0000u; return v.f;
}
// sigmoid(z) = 1/(1+2^(-z*log2e))
__device__ __forceinline__ float fsigmoid(float z) {
  return __builtin_amdgcn_rcpf(1.f + fexp2(z * -1.44269504088896f));
}

// Pack all five f32 weights into fp8 MFMA-A fragment order, K=128 tiles:
// P[off + tile*2048 + lane*32 + j] =
//   e4m3(WSC * W[kb*128 + (lane>>4)*32 + j][n16*16 + (lane&15)]), j=0..31
__global__ void pack_all(const float* __restrict__ Wu, const float* __restrict__ Wg,
                         const float* __restrict__ A,  const float* __restrict__ W1,
                         const float* __restrict__ W2, unsigned char* __restrict__ P) {
  const int gid = blockIdx.x * blockDim.x + threadIdx.x;
  const int l = gid & 63;
  int tile = gid >> 6;
  const float* W; int N; unsigned off; int t;
  if      (tile <  72) { W = Wu; N = 384;  off = OFF_WU; t = tile;       }
  else if (tile < 144) { W = Wg; N = 384;  off = OFF_WG; t = tile - 72;  }
  else if (tile < 216) { W = A;  N = 384;  off = OFF_A;  t = tile - 144; }
  else if (tile < 504) { W = W1; N = 1536; off = OFF_W1; t = tile - 216; }
  else if (tile < 792) { W = W2; N = 384;  off = OFF_W2; t = tile - 504; }
  else return;
  const int ntn = N >> 4;
  const int kb  = t / ntn, n16 = t % ntn;
  const int krow = kb * 128 + ((l >> 4) << 5);
  const int col  = n16 * 16 + (l & 15);
  unsigned pk[8];
  #pragma unroll
  for (int d = 0; d < 8; ++d) {
    unsigned v = 0;
    #pragma unroll
    for (int j = 0; j < 4; ++j)
      v |= (unsigned)f2e4(W[(size_t)(krow + d * 4 + j) * N + col] * WSC) << (8 * j);
    pk[d] = v;
  }
  unsigned* dst = reinterpret_cast<unsigned*>(P + off + ((size_t)t << 11) + (l << 5));
  #pragma unroll
  for (int d = 0; d < 8; ++d) dst[d] = pk[d];
}

// acc[4][2] += scale * W^T(2 chan-tiles, fp8 K=128) * X^T(LDS fp8, 4 pixel-
// tiles) via MX-scaled MFMA; scl is the E8M0 per-block scale for the weight
// operand (power-of-2 dequant folded into HW). NKB = K/128 blocks.
template <int NKB>
__device__ __forceinline__ void gemm_acc(const unsigned char* sb,
                                         const unsigned char* __restrict__ wt,
                                         int kb0, int ntn, int n16base,
                                         int lane, unsigned scl, f4_t acc[4][2]) {
  const int r    = lane & 15;
  const int koff = (lane >> 4) << 5;        // byte offset of 32-k group
  __builtin_amdgcn_s_setprio(1);
  #pragma unroll 1
  for (int kb = 0; kb < NKB; ++kb) {
    const int ac = kb * 128 + koff;
    i32x8 p[4];
    #pragma unroll
    for (int pt = 0; pt < 4; ++pt)
      p[pt] = *reinterpret_cast<const i32x8*>(&sb[(pt * 16 + r) * SBB + ac]);
    const unsigned char* bt =
        wt + (((size_t)((kb0 + kb) * ntn + n16base)) << 11) + (lane << 5);
    #pragma unroll
    for (int ct = 0; ct < 2; ++ct) {
      const i32x8 w = *reinterpret_cast<const i32x8*>(bt + (ct << 11));
      #pragma unroll
      for (int pt = 0; pt < 4; ++pt)
        acc[pt][ct] = __builtin_amdgcn_mfma_scale_f32_16x16x128_f8f6f4(
            w, p[pt], acc[pt][ct], 0 /*fmtA=fp8*/, 0 /*fmtB=fp8*/,
            0, (int)scl, 0, (int)SCL1);
    }
  }
  __builtin_amdgcn_s_setprio(0);
}

// Merged dual-weight gemm (Wg -> accG @ sclG, Wu -> accU @ sclU): shares the
// X^T fragment loads between both weight streams. Per-accumulator MFMA order
// identical to two sequential gemm_acc calls -> bit-identical results.
__device__ __forceinline__ void gemm_acc2(const unsigned char* sb,
                                          const unsigned char* __restrict__ wtG,
                                          const unsigned char* __restrict__ wtU,
                                          int ntn, int n16base, int lane,
                                          unsigned sclG, unsigned sclU,
                                          f4_t accG[4][2], f4_t accU[4][2]) {
  const int r    = lane & 15;
  const int koff = (lane >> 4) << 5;
  __builtin_amdgcn_s_setprio(1);
  #pragma unroll 1
  for (int kb = 0; kb < 3; ++kb) {
    const int ac = kb * 128 + koff;
    i32x8 p[4];
    #pragma unroll
    for (int pt = 0; pt < 4; ++pt)
      p[pt] = *reinterpret_cast<const i32x8*>(&sb[(pt * 16 + r) * SBB + ac]);
    const size_t toff = (((size_t)(kb * ntn + n16base)) << 11) + (lane << 5);
    #pragma unroll
    for (int ct = 0; ct < 2; ++ct) {
      const i32x8 wG = *reinterpret_cast<const i32x8*>(wtG + toff + (ct << 11));
      const i32x8 wU = *reinterpret_cast<const i32x8*>(wtU + toff + (ct << 11));
      #pragma unroll
      for (int pt = 0; pt < 4; ++pt) {
        accG[pt][ct] = __builtin_amdgcn_mfma_scale_f32_16x16x128_f8f6f4(
            wG, p[pt], accG[pt][ct], 0, 0, 0, (int)sclG, 0, (int)SCL1);
        accU[pt][ct] = __builtin_amdgcn_mfma_scale_f32_16x16x128_f8f6f4(
            wU, p[pt], accU[pt][ct], 0, 0, 0, (int)sclU, 0, (int)SCL1);
      }
    }
  }
  __builtin_amdgcn_s_setprio(0);
}

// write pre-scaled C/D tile into fp8 LDS [pix][chan]: 2 cvt_pk + 1 write/quad.
__device__ __forceinline__ void write_tile(unsigned char* sb, const f4_t t[4][2],
                                           int ch0, int lane) {
  const int pixb = lane & 15;
  #pragma unroll
  for (int pt = 0; pt < 4; ++pt) {
    const int pix = pt * 16 + pixb;
    #pragma unroll
    for (int ct = 0; ct < 2; ++ct) {
      const unsigned v = pk4e4(t[pt][ct][0], t[pt][ct][1],
                               t[pt][ct][2], t[pt][ct][3]);
      *reinterpret_cast<unsigned*>(&sb[pix * SBB + ch0 + ct * 16]) = v;
    }
  }
}

__device__ __forceinline__ void zero_acc(f4_t a[4][2]) {
  #pragma unroll
  for (int pt = 0; pt < 4; ++pt)
    #pragma unroll
    for (int ct = 0; ct < 2; ++ct) a[pt][ct] = (f4_t){0.f, 0.f, 0.f, 0.f};
}

__global__ __launch_bounds__(NTHR)
__attribute__((amdgpu_waves_per_eu(3)))
void cssm_main(
    const float* __restrict__ x,
    const float* __restrict__ n1s, const float* __restrict__ n1b,
    const float* __restrict__ bu, const float* __restrict__ bg,
    const float* __restrict__ n2s, const float* __restrict__ n2b,
    const float* __restrict__ b1, const float* __restrict__ b2,
    const unsigned char* __restrict__ wp,
    float* __restrict__ out) {
  __shared__ unsigned char sm[3 * HBUF];    // bA | bB | bC (27KB each)
  __shared__ unsigned short hd[BMROWS * SH];// h8 (bf16, same-thread reread)
  __shared__ float part[BMROWS][12][2];     // per-(pixel,chan-slot) LN2 partials
  __shared__ float srow[BMROWS][2];         // LN2 mu, rs per pixel
  unsigned char* bA = sm;                   // xn -> h ping -> xn2
  unsigned char* bB = sm + HBUF;            // h pong -> m even chunks
  unsigned char* bC = sm + 2 * HBUF;        // m odd chunks

  const int tid = threadIdx.x;
  const int lane = tid & 63;
  const int nw = tid >> 6;                  // chan-slot 0..11: chans nw*32..+31
  const int r0 = blockIdx.x * BMROWS;
  const int pixb = lane & 15;
  const int ch0  = nw * 32 + ((lane >> 4) << 2);   // byte == chan index

  // ---------------- Phase A: LN1(x) -> bA (fp8, ASC-scaled) ----------------
  if (tid < 512) {
    const int row = tid >> 3, seg = tid & 7;     // 8 thr/row, 48 elems each
    const float* xr = x + (size_t)(r0 + row) * CCH + seg * 48;
    float v[48];
    float s = 0.f, s2 = 0.f;
    #pragma unroll
    for (int i = 0; i < 12; ++i) {
      const f4_t t = reinterpret_cast<const f4_t*>(xr)[i];
      #pragma unroll
      for (int j = 0; j < 4; ++j) { const float f = t[j]; v[i * 4 + j] = f; s += f; s2 += f * f; }
    }
    #pragma unroll
    for (int o = 1; o < 8; o <<= 1) { s += __shfl_xor(s, o, 64); s2 += __shfl_xor(s2, o, 64); }
    const float mu = s * (1.f / CCH);
    const float rs = rsqrtf(fmaxf(s2 * (1.f / CCH) - mu * mu, 0.f) + LNEPS);
    #pragma unroll
    for (int g8 = 0; g8 < 6; ++g8) {
      float w[8];
      #pragma unroll
      for (int j = 0; j < 8; ++j) {
        const int colc = seg * 48 + g8 * 8 + j;
        w[j] = ((v[g8 * 8 + j] - mu) * rs * n1s[colc] + n1b[colc]) * ASC;
      }
      uint2 pk;
      pk.x = pk4e4(w[0], w[1], w[2], w[3]);
      pk.y = pk4e4(w[4], w[5], w[6], w[7]);
      *reinterpret_cast<uint2*>(&bA[row * SBB + seg * 48 + g8 * 8]) = pk;
    }
  }
  __syncthreads();

  // ------- Phase A2: merged Wg/Wu gemm -> g (true), cf (ASC); h1 -> bB -----
  f4_t acc[4][2], gf[4][2], cf[4][2];
  zero_acc(gf);                             // accG
  zero_acc(acc);                            // accU
  gemm_acc2(bA, wp + OFF_WG, wp + OFF_WU, 24, nw * 2, lane, SCLDQ, SCLA6,
            gf, acc);
  #pragma unroll
  for (int ct = 0; ct < 2; ++ct) {
    const f4_t bgq = *reinterpret_cast<const f4_t*>(&bg[ch0 + ct * 16]);
    const f4_t bq  = *reinterpret_cast<const f4_t*>(&bu[ch0 + ct * 16]);
    f4_t buA;
    #pragma unroll
    for (int j = 0; j < 4; ++j) buA[j] = bq[j] * ASC;
    #pragma unroll
    for (int pt = 0; pt < 4; ++pt)
      #pragma unroll
      for (int j = 0; j < 4; ++j) {
        const float g = fsigmoid(gf[pt][ct][j] + bgq[j]);
        gf[pt][ct][j] = g;
        cf[pt][ct][j] = (1.f - g) * (acc[pt][ct][j] + buA[j]);
      }
  }
  write_tile(bB, cf, ch0, lane);            // H1 = ASC*c  (bA reads done)
  __syncthreads();

  // ----- Phase B: H' = g*out + cf (out pre-scaled to ASC units by HW) ------
  {
    unsigned char* cur = bB;
    unsigned char* alt = bA;
    #pragma unroll 1
    for (int stp = 0; stp < 7; ++stp) {     // h2..h8
      zero_acc(acc);
      gemm_acc<3>(cur, wp + OFF_A, 0, 24, nw * 2, lane, SCLA6, acc);
      #pragma unroll
      for (int pt = 0; pt < 4; ++pt)
        #pragma unroll
        for (int ct = 0; ct < 2; ++ct)
          #pragma unroll
          for (int j = 0; j < 4; ++j)
            acc[pt][ct][j] = gf[pt][ct][j] * acc[pt][ct][j] + cf[pt][ct][j];
      if (stp < 6) {
        write_tile(alt, acc, ch0, lane);    // write buffer nobody is reading
        unsigned char* t = cur; cur = alt; alt = t;
        __syncthreads();
      }
    }
  }
  // last recurrence reads hit bB (fenced later); bA reads fenced at stp5.

  // ------- Phase C: h8 -> hd (bf16); y = x + h8 (regs); LN2 -> xn2 in bA ---
  #pragma unroll
  for (int pt = 0; pt < 4; ++pt) {
    const int pix = pt * 16 + pixb;
    float s = 0.f, s2 = 0.f;
    #pragma unroll
    for (int ct = 0; ct < 2; ++ct) {
      const size_t pos = (size_t)(r0 + pix) * CCH + ch0 + ct * 16;
      const f4_t xq = *reinterpret_cast<const f4_t*>(&x[pos]);
      uint2 hq;
      float h0 = acc[pt][ct][0] * IASC, h1 = acc[pt][ct][1] * IASC;
      float h2 = acc[pt][ct][2] * IASC, h3 = acc[pt][ct][3] * IASC;
      hq.x = pack2(h0, h1); hq.y = pack2(h2, h3);
      *reinterpret_cast<uint2*>(&hd[pix * SH + ch0 + ct * 16]) = hq;
      const float y0 = xq[0] + h0, y1 = xq[1] + h1;
      const float y2 = xq[2] + h2, y3 = xq[3] + h3;
      acc[pt][ct][0] = y0; acc[pt][ct][1] = y1;
      acc[pt][ct][2] = y2; acc[pt][ct][3] = y3;
      s += y0 + y1 + y2 + y3;
      s2 += y0 * y0 + y1 * y1 + y2 * y2 + y3 * y3;
    }
    s += __shfl_xor(s, 16, 64); s2 += __shfl_xor(s2, 16, 64);
    s += __shfl_xor(s, 32, 64); s2 += __shfl_xor(s2, 32, 64);
    if (lane < 16) { part[pix][nw][0] = s; part[pix][nw][1] = s2; }
  }
  __syncthreads();
  if (tid < BMROWS) {
    float s = 0.f, s2 = 0.f;
    #pragma unroll
    for (int w = 0; w < 12; ++w) { s += part[tid][w][0]; s2 += part[tid][w][1]; }
    const float mu = s * (1.f / CCH);
    srow[tid][0] = mu;
    srow[tid][1] = rsqrtf(fmaxf(s2 * (1.f / CCH) - mu * mu, 0.f) + LNEPS);
  }
  __syncthreads();
  {
    f4_t scq[2], bsq[2];
    #pragma unroll
    for (int ct = 0; ct < 2; ++ct) {
      const f4_t sc = *reinterpret_cast<const f4_t*>(&n2s[ch0 + ct * 16]);
      const f4_t bs = *reinterpret_cast<const f4_t*>(&n2b[ch0 + ct * 16]);
      #pragma unroll
      for (int j = 0; j < 4; ++j) { scq[ct][j] = sc[j] * ASC; bsq[ct][j] = bs[j] * ASC; }
    }
    #pragma unroll
    for (int pt = 0; pt < 4; ++pt) {
      const int pix = pt * 16 + pixb;
      const float mu = srow[pix][0], rs = srow[pix][1];
      #pragma unroll
      for (int ct = 0; ct < 2; ++ct)
        #pragma unroll
        for (int j = 0; j < 4; ++j)
          acc[pt][ct][j] = (acc[pt][ct][j] - mu) * rs * scq[ct][j] + bsq[ct][j];
    }
    write_tile(bA, acc, ch0, lane);         // ASC*xn2 (bA reads fenced at stp5)
  }
  __syncthreads();

  // ------- Phase D: MLP in 4 HID-chunks, m double-buffered bB/bC -----------
  f4_t aco[4][2];
  zero_acc(aco);                            // MFMA-only until E -> AGPR
  #pragma unroll 1
  for (int ch = 0; ch < 4; ++ch) {
    unsigned char* buf = (ch & 1) ? bC : bB;
    zero_acc(acc);
    gemm_acc<3>(bA, wp + OFF_W1, 0, 96, ch * 24 + nw * 2, lane, SCLDQ, acc);
    #pragma unroll
    for (int ct = 0; ct < 2; ++ct) {
      const f4_t b1q = *reinterpret_cast<const f4_t*>(&b1[ch * 384 + ch0 + ct * 16]);
      #pragma unroll
      for (int pt = 0; pt < 4; ++pt)
        #pragma unroll
        for (int j = 0; j < 4; ++j) {
          // gelu(z) = z / (1 + 2^(-2.3021178*(z + 0.044715 z^3))); store ASC*gelu
          const float z = acc[pt][ct][j] + b1q[j];        // true units (HW DQ)
          const float m = z * z;
          const float t = z * fmaf(m, 0.044715f, 1.0f);
          const float e = fexp2(t * -2.30211774f);
          acc[pt][ct][j] = (z * ASC) * __builtin_amdgcn_rcpf(1.f + e);
        }
    }
    write_tile(buf, acc, ch0, lane);
    __syncthreads();                        // buf complete; prev buf readers
                                            // passed the previous barrier
    gemm_acc<3>(buf, wp + OFF_W2, ch * 3, 24, nw * 2, lane, SCLDQ, aco);
  }

  // ------- Phase E: out = x + h8 + mlp + b2 (aco already true units) -------
  {
    f4_t b2q[2];
    #pragma unroll
    for (int ct = 0; ct < 2; ++ct)
      b2q[ct] = *reinterpret_cast<const f4_t*>(&b2[ch0 + ct * 16]);
    #pragma unroll
    for (int pt = 0; pt < 4; ++pt) {
      const int pix = pt * 16 + pixb;
      #pragma unroll
      for (int ct = 0; ct < 2; ++ct) {
        const size_t pos = (size_t)(r0 + pix) * CCH + ch0 + ct * 16;
        const f4_t xq = *reinterpret_cast<const f4_t*>(&x[pos]);
        const uint2 hq = *reinterpret_cast<const uint2*>(&hd[pix * SH + ch0 + ct * 16]);
        f4_t o;
        o[0] = xq[0] + ulo(hq.x) + aco[pt][ct][0] + b2q[ct][0];
        o[1] = xq[1] + uhi(hq.x) + aco[pt][ct][1] + b2q[ct][1];
        o[2] = xq[2] + ulo(hq.y) + aco[pt][ct][2] + b2q[ct][2];
        o[3] = xq[3] + uhi(hq.y) + aco[pt][ct][3] + b2q[ct][3];
        *reinterpret_cast<f4_t*>(&out[pos]) = o;
      }
    }
  }
}

extern "C" void kernel_launch(void* const* d_in, const int* in_sizes, int n_in,
                              void* d_out, int out_size, void* d_ws, size_t ws_size,
                              hipStream_t stream) {
  const float* x   = (const float*)d_in[0];
  const float* n1s = (const float*)d_in[1];
  const float* n1b = (const float*)d_in[2];
  const float* Wu  = (const float*)d_in[3];
  const float* bu  = (const float*)d_in[4];
  const float* Wg  = (const float*)d_in[5];
  const float* bg  = (const float*)d_in[6];
  const float* A   = (const float*)d_in[7];
  const float* n2s = (const float*)d_in[8];
  const float* n2b = (const float*)d_in[9];
  const float* W1  = (const float*)d_in[10];
  const float* b1  = (const float*)d_in[11];
  const float* W2  = (const float*)d_in[12];
  const float* b2  = (const float*)d_in[13];
  unsigned char* wp = (unsigned char*)d_ws;
  float* out = (float*)d_out;

  // pack all weights to fp8 K=128 fragment order (792 tiles * 64 lanes)
  pack_all<<<(792 * 64) / 256, 256, 0, stream>>>(Wu, Wg, A, W1, W2, wp);

  cssm_main<<<NPIX / BMROWS, NTHR, 0, stream>>>(
      x, n1s, n1b, bu, bg, n2s, n2b, b1, b2, wp, out);
}